// Round 8
// baseline (288.568 us; speedup 1.0000x reference)
//
#include <hip/hip_runtime.h>

namespace {
constexpr int CC    = 10;                  // cluster gap window C
constexpr int TT    = 500;                 // time steps
constexpr int NN    = 128;                 // neurons per batch row
constexpr int G     = 10;                  // t-segments per trace
constexpr int LSEG  = TT / G;              // 50 core steps
constexpr int HALO  = CC;                  // 10
constexpr int NCH   = 7;                   // 7 chunks of 10 rows cover [-10, 60)
constexpr int NSLOT = 10;                  // ws record: 5 cluster maxes + 5 scalars
constexpr int MAXG  = TT / (CC + 1) + 1;   // 46 max global clusters
}

// ---------------- kernel A: continuous ring-pipelined scan ----------------
// Ring of 4 register chunk-buffers, issue distance 3 (~1500 cy cover > 900 cy
// HBM latency). Scan-before-issue each iteration: the ring-slot WAR pins the
// schedule; no barrier, no vmcnt(0) drain anywhere in the loop. Steady state:
// 20 dword loads (5 KB) outstanding per wave at all times.
__global__ __launch_bounds__(128, 5)
void seg_scan_kernel(const float* __restrict__ vmem, float* __restrict__ ws) {
    const int s   = blockIdx.x;            // segment 0..9
    const int b   = blockIdx.y;
    const int tid = threadIdx.x;           // neuron 0..127
    const int a   = s * LSEG;
    const float* __restrict__ col = vmem + (size_t)b * TT * NN + tid;

    __shared__ float stg[5 * NN];          // 2.5 KB: open-cluster max scratch

    float rg[4][10];                       // ring: 40 data VGPRs
    float hist[10];                        // v delay line, compile-time indexed

    // prologue: issue chunks 0..2 (30 loads in flight)
    #pragma unroll
    for (int k = 0; k < 3; ++k) {
        #pragma unroll
        for (int j = 0; j < 10; ++j) {
            int t = a - HALO + 10 * k + j;
            t = t < 0 ? 0 : (t > TT - 1 ? TT - 1 : t);
            rg[k][j] = col[(size_t)t * NN];
        }
    }

    int   ls = -(1 << 20), lcount = 0, hdne = 0, tmn = 0, hasu = 0;
    float ccm = -1e30f, rmax = -1e30f, hdm = -1e30f, vmx = -1e30f, m0 = -1e30f;

    #pragma unroll
    for (int c = 0; c < NCH; ++c) {
        // ---- scan chunk c (waits only chunk c's 10 loads; 20 stay in flight) ----
        #pragma unroll
        for (int j = 0; j < 10; ++j) {
            const int r   = 10 * c + j;    // compile-time
            const int ofs = r - HALO;
            const int t   = a + ofs;
            float x = rg[c & 3][j];
            if (s == 0 && r < HALO) x = -1.0f;            // before t=0
            if (s == G - 1 && ofs >= LSEG) x = -1.0f;     // past t=T
            const bool spike = x >= 0.0f;
            if (ofs >= 0 && ofs < LSEG) {                 // core accounting
                const float rm2     = fmaxf(rmax, x);
                const bool  recent  = (t - ls <= CC);
                const bool  isStart = spike && !recent;
                const bool  contS   = spike && recent;
                const bool  hd      = contS && (lcount == 0);
                hdm  = hd ? fmaxf(hdm, rm2) : hdm;
                hdne = hd ? 1 : hdne;
                const float folded = fmaxf(ccm, rm2);
                ccm  = isStart ? x : ((contS && lcount > 0) ? folded : ccm);
                lcount += isStart ? 1 : 0;
                rmax = spike ? -1e30f : rm2;
                if (x > vmx) { vmx = x; tmn = t; }        // strict >: first argmax
                const int idx = lcount > 0 ? lcount - 1 : 0;
                stg[idx * NN + tid] = ccm;                // final write per slot wins
            }
            if (spike) ls = t;                            // halo spikes count for ls
            if (r >= 2 * HALO) {                          // eval u = t-10 in [a, a+50)
                const float vu = hist[r % 10];            // v[t-10], register
                const bool  um = ls < t - 2 * CC;
                hasu = um ? 1 : hasu;
                m0   = um ? fmaxf(m0, vu) : m0;
            }
            hist[r % 10] = x;
        }
        // ---- issue chunk c+3 into the slot chunk c just freed ((c+3)&3 == (c-1)&3) ----
        if (c + 3 < NCH) {
            #pragma unroll
            for (int j = 0; j < 10; ++j) {
                int t = a - HALO + 10 * (c + 3) + j;
                t = t < 0 ? 0 : (t > TT - 1 ? TT - 1 : t);
                rg[(c + 3) & 3][j] = col[(size_t)t * NN];
            }
        }
    }

    // ---- coalesced output: 10 rows of 512 B ----
    float* __restrict__ wsl = ws + (size_t)(b * G + s) * NSLOT * NN + tid;
    #pragma unroll
    for (int i = 0; i < 5; ++i)
        wsl[i * NN] = (i < lcount) ? stg[i * NN + tid] : 0.0f;
    const int packed = lcount | (hdne << 3) | (hasu << 4) | (tmn << 5);
    wsl[5 * NN] = __int_as_float(packed);
    wsl[6 * NN] = hdm;     // head-piece max
    wsl[7 * NN] = rmax;    // tail gap max (since last core spike)
    wsl[8 * NN] = vmx;
    wsl[9 * NN] = m0;
}

// ---------------- kernel B: merge segments + loss (1 wave per 64 neurons) ----------------
__global__ __launch_bounds__(64)
void merge_kernel(const float* __restrict__ vmem, const float* __restrict__ ws,
                  const int* __restrict__ labels, float* __restrict__ out) {
    const int bb = blockIdx.x, lane = threadIdx.x;
    const int b = bb >> 1, n = ((bb & 1) << 6) | lane;
    __shared__ float gl[MAXG * 64];        // 11.8 KB compact global cluster list
    __shared__ float wb[512];              // pass-2 column staging

    // streaming double-buffered ws reads: 10 values per segment in flight
    const float* __restrict__ wsb = ws + (size_t)b * G * NSLOT * NN + n;
    float f[2][10];
    auto loadSeg = [&](int slot, int s2) {
        const float* p = wsb + (size_t)s2 * NSLOT * NN;
        #pragma unroll
        for (int i = 0; i < 10; ++i) f[slot][i] = p[i * NN];
    };
    loadSeg(0, 0);

    int g = 0, g_nc = 0, g_hasu = 0, g_tm = 0;
    bool open = false; float cur = -1e30f, ptg = -1e30f;
    float g_vmax = -1e30f, g_m0 = -1e30f;
    #pragma unroll
    for (int s2 = 0; s2 < G; ++s2) {
        if (s2 + 1 < G) loadSeg((s2 + 1) & 1, s2 + 1);
        const float (&d)[10] = f[s2 & 1];
        const int pk = __float_as_int(d[5]);
        const int k = pk & 7, hne = (pk >> 3) & 1;
        g_nc += k; g_hasu |= (pk >> 4) & 1;
        if (d[8] > g_vmax) { g_vmax = d[8]; g_tm = pk >> 5; }
        if (d[9] > g_m0) g_m0 = d[9];
        if (open) {
            if (hne) { cur = fmaxf(cur, fmaxf(ptg, d[6])); ptg = d[7]; }
            if (k > 0 || !hne) { gl[g * 64 + lane] = cur; ++g; open = false; }
        }
        if (k > 0) {
            #pragma unroll
            for (int i = 0; i < 4; ++i)
                if (i < k - 1) { gl[g * 64 + lane] = d[i]; ++g; }
            float last = d[4];                 // select d[k-1]
            if (k == 1) last = d[0];
            else if (k == 2) last = d[1];
            else if (k == 3) last = d[2];
            else if (k == 4) last = d[3];
            cur = last; open = true; ptg = d[7];
        }
    }
    if (open) { gl[g * 64 + lane] = cur; ++g; }        // g == g_nc

    const int label = labels[b * NN + n];

    // pass-2 m_rest: wave-cooperative, rare
    const bool need2 = (label > g_nc) && g_hasu && (label - g_nc >= 2);
    float mrest = g_vmax;                              // full2 surrogate default
    unsigned long long bal = __ballot(need2);
    const float* colbase = vmem + (size_t)b * TT * NN;
    while (bal) {
        const int fl = __ffsll((unsigned long long)bal) - 1;
        bal &= bal - 1;
        const int   nf    = ((bb & 1) << 6) | fl;      // flagged neuron
        const int   tmf   = __shfl(g_tm, fl);
        const float vmaxf = __shfl(g_vmax, fl);
        #pragma unroll
        for (int j = 0; j < 8; ++j) {                  // stage column: 8 loads/lane
            const int t = lane * 8 + j;
            wb[t] = (t < TT) ? colbase[(size_t)t * NN + nf] : -1.0f;
        }
        __syncthreads();                               // single wave: cheap
        int ls2 = -1000, lh = 0; float lm = -1e30f;
        const int u0 = lane * 8;
        for (int t2 = u0 - 10; t2 < u0 + 18; ++t2) {
            const float v = (t2 >= 0 && t2 < 512) ? wb[t2] : -1.0f;
            if (v >= 0.0f) ls2 = t2;
            const int u = t2 - 10;
            if (u >= u0 && u < u0 + 8 && u < TT) {
                if (ls2 < u - 10 && (u < tmf - CC / 2 || u > tmf + CC / 2)) {
                    lh = 1; const float vu = wb[u]; if (vu > lm) lm = vu;
                }
            }
        }
        #pragma unroll
        for (int off = 32; off > 0; off >>= 1) {       // wave reduce
            lm = fmaxf(lm, __shfl_down(lm, off));
            lh |= __shfl_down(lh, off);
        }
        const float res = __shfl(lh ? lm : vmaxf, 0);
        if (lane == fl) mrest = res;
        __syncthreads();
    }

    // branch select
    float contrib = 0.0f;
    if (label > g_nc) {
        if (!g_hasu) contrib = g_vmax;                 // full0 -> vmax
        else {
            const float dE = (float)(label - g_nc);    // >= 1
            contrib = -((g_m0 + (dE - 1.0f) * mrest) / dE);
        }
    } else if (label < g_nc) {
        const int kk = g_nc - label;                   // 1..nc
        float ssum = 0.0f;
        for (int i = 0; i < kk; ++i) {                 // sum kk smallest cluster maxes
            float mn = 1e30f; int mj = 0;
            for (int jj = 0; jj < g_nc; ++jj) {
                const float x = gl[jj * 64 + lane];
                if (x < mn) { mn = x; mj = jj; }
            }
            ssum += mn; gl[mj * 64 + lane] = 1e30f;
        }
        contrib = ssum / (float)kk;
    }

    out[1 + b * NN + n] = (float)g_nc;                 // spike_output

    float w = contrib;
    #pragma unroll
    for (int off = 32; off > 0; off >>= 1) w += __shfl_down(w, off);
    if (lane == 0) atomicAdd(out, w);
}

extern "C" void kernel_launch(void* const* d_in, const int* in_sizes, int n_in,
                              void* d_out, int out_size, void* d_ws, size_t ws_size,
                              hipStream_t stream) {
    const float* vmem   = (const float*)d_in[0];
    // d_in[1] (vlastmem) and d_in[3] (ratio) are unused by the reference forward.
    const int*   labels = (const int*)d_in[2];
    float*       out    = (float*)d_out;
    float*       ws     = (float*)d_ws;   // 256*10*10*128*4 = 13.1 MB

    const int B = in_sizes[2] / NN;       // 256

    hipMemsetAsync(out, 0, sizeof(float), stream);     // zero the loss accumulator
    hipLaunchKernelGGL(seg_scan_kernel, dim3(G, B), dim3(NN), 0, stream, vmem, ws);
    hipLaunchKernelGGL(merge_kernel, dim3(2 * B), dim3(64), 0, stream, vmem, ws, labels, out);
}

// Round 9
// 244.533 us; speedup vs baseline: 1.1801x; 1.1801x over previous
//
#include <hip/hip_runtime.h>

namespace {
constexpr int CC    = 10;                  // cluster gap window C
constexpr int TT    = 500;                 // time steps
constexpr int NN    = 128;                 // neurons per batch row
constexpr int G     = 10;                  // t-segments per trace
constexpr int LSEG  = TT / G;              // 50 core steps
constexpr int HALO  = CC;                  // 10
constexpr int ROWS  = LSEG + 2 * HALO;     // 70 scanned rows
constexpr int CHR   = 8;                   // rows per chunk
constexpr int NCHK  = 9;                   // 9 chunks = 72 rows (last 2 padded)
constexpr int RING  = 4;                   // LDS ring slots per wave
constexpr int NSLOT = 10;                  // ws record: 5 cluster maxes + 5 scalars
constexpr int MAXG  = TT / (CC + 1) + 1;   // 46 max global clusters
}

// ---------------- kernel A: global_load_lds ring + manual vmcnt pipeline ----------------
// Per-WAVE private LDS ring (no barriers). Stage chunk = 8 rows x 64 neurons via two
// width-16 global_load_lds (1 KB each, LDS dst = uniform base + lane*16). Manual
// s_waitcnt vmcnt(N) keeps 2 chunks (4 instr) permanently in flight -- the compiler
// has no VGPR dependency to guard, so it cannot insert a drain.
__global__ __launch_bounds__(128, 4)
void seg_scan_kernel(const float* __restrict__ vmem, float* __restrict__ ws) {
    const int s    = blockIdx.x;           // segment 0..9
    const int b    = blockIdx.y;
    const int tid  = threadIdx.x;
    const int w    = tid >> 6;             // wave 0/1 (independent; neurons w*64..)
    const int lane = tid & 63;
    const int a    = s * LSEG;

    __shared__ __align__(16) float tiles[2][RING * CHR * 64];  // 2 x 8 KB rings
    __shared__ float stg[2][5 * 64];                           // open-cluster maxes
    float* tw = tiles[w];
    float* sw = stg[w];

    // lane -> (row-in-quad, 16B column piece) for the scattered gather
    const int rsub = lane >> 4;            // 0..3
    const int csub = (lane & 15) * 4;      // float offset within 64-neuron row
    const float* gbase = vmem + (size_t)b * TT * NN + w * 64 + csub;

    auto issue4 = [&](int t0, float* ldst) {       // stage rows t0..t0+3 (clamped)
        int t = t0 + rsub;
        t = t < 0 ? 0 : (t > TT - 1 ? TT - 1 : t);
        const float* gp = gbase + (size_t)t * NN;
        __builtin_amdgcn_global_load_lds(
            (const __attribute__((address_space(1))) void*)gp,
            (__attribute__((address_space(3))) void*)ldst, 16, 0, 0);
    };
    auto issueChunk = [&](int c) {
        const int t0 = a - HALO + CHR * c;
        float* slot = tw + (c % RING) * (CHR * 64);
        issue4(t0,     slot);
        issue4(t0 + 4, slot + 4 * 64);
    };

    int   ls = -(1 << 20), lcount = 0, hdne = 0, tmn = 0, hasu = 0;
    float ccm = -1e30f, rmax = -1e30f, hdm = -1e30f, vmx = -1e30f, m0 = -1e30f;
    float h[10];                                   // delay line, const-indexed -> regs

    issueChunk(0); issueChunk(1); issueChunk(2);   // 6 instr (6 KB) in flight

    #pragma unroll
    for (int c = 0; c < NCHK; ++c) {
        // wait until chunk c staged; leave chunks c+1, c+2 in flight (N = 4/2/0)
        constexpr int imm_dc = 0xF70;              // lgkmcnt/expcnt = don't care
        if (c < NCHK - 2)      __builtin_amdgcn_s_waitcnt(4 | imm_dc);
        else if (c == NCHK - 2) __builtin_amdgcn_s_waitcnt(2 | imm_dc);
        else                    __builtin_amdgcn_s_waitcnt(0 | imm_dc);

        const float* slot = tw + (c % RING) * (CHR * 64);
        #pragma unroll
        for (int j = 0; j < CHR; ++j) {
            const int r = CHR * c + j;             // compile-time
            if (r >= ROWS) continue;               // pad rows 70,71
            const int ofs = r - HALO;
            const int t   = a + ofs;
            float x = slot[j * 64 + lane];
            if (s == 0 && r < HALO)          x = -1.0f;   // before t=0
            if (s == G - 1 && ofs >= LSEG)   x = -1.0f;   // past t=T
            const bool spike = x >= 0.0f;
            if (ofs >= 0 && ofs < LSEG) {          // core accounting
                const float rm2     = fmaxf(rmax, x);
                const bool  recent  = (t - ls <= CC);
                const bool  isStart = spike && !recent;
                const bool  contS   = spike && recent;
                const bool  hd      = contS && (lcount == 0);
                hdm  = hd ? fmaxf(hdm, rm2) : hdm;
                hdne = hd ? 1 : hdne;
                const float folded = fmaxf(ccm, rm2);
                ccm  = isStart ? x : ((contS && lcount > 0) ? folded : ccm);
                lcount += isStart ? 1 : 0;
                rmax = spike ? -1e30f : rm2;
                if (x > vmx) { vmx = x; tmn = t; } // strict >: first argmax
                const int idx = lcount > 0 ? lcount - 1 : 0;
                sw[idx * 64 + lane] = ccm;         // final write per slot wins
            }
            if (spike) ls = t;                     // halo spikes count for ls
            if (r >= 2 * HALO) {                   // eval u = t-10 in [a, a+50)
                const float vu = h[r % 10];        // v[t-10] (read before overwrite)
                const bool  um = ls < t - 2 * CC;
                hasu = um ? 1 : hasu;
                m0   = um ? fmaxf(m0, vu) : m0;
            }
            h[r % 10] = x;
        }
        if (c + 3 < NCHK) issueChunk(c + 3);       // refill the ring
    }

    // ---- coalesced output: 10 rows of 512 B ----
    float* __restrict__ wsl = ws + (size_t)(b * G + s) * NSLOT * NN + tid;
    #pragma unroll
    for (int i = 0; i < 5; ++i)
        wsl[i * NN] = (i < lcount) ? sw[i * 64 + lane] : 0.0f;
    const int packed = lcount | (hdne << 3) | (hasu << 4) | (tmn << 5);
    wsl[5 * NN] = __int_as_float(packed);
    wsl[6 * NN] = hdm;     // head-piece max
    wsl[7 * NN] = rmax;    // tail gap max (since last core spike)
    wsl[8 * NN] = vmx;
    wsl[9 * NN] = m0;
}

// ---------------- kernel B: merge segments + loss (1 wave per 64 neurons) ----------------
__global__ __launch_bounds__(64)
void merge_kernel(const float* __restrict__ vmem, const float* __restrict__ ws,
                  const int* __restrict__ labels, float* __restrict__ out) {
    const int bb = blockIdx.x, lane = threadIdx.x;
    const int b = bb >> 1, n = ((bb & 1) << 6) | lane;
    __shared__ float gl[MAXG * 64];        // 11.8 KB compact global cluster list
    __shared__ float wb[512];              // pass-2 column staging

    // streaming double-buffered ws reads: 10 values per segment in flight
    const float* __restrict__ wsb = ws + (size_t)b * G * NSLOT * NN + n;
    float f[2][10];
    auto loadSeg = [&](int slot, int s2) {
        const float* p = wsb + (size_t)s2 * NSLOT * NN;
        #pragma unroll
        for (int i = 0; i < 10; ++i) f[slot][i] = p[i * NN];
    };
    loadSeg(0, 0);

    int g = 0, g_nc = 0, g_hasu = 0, g_tm = 0;
    bool open = false; float cur = -1e30f, ptg = -1e30f;
    float g_vmax = -1e30f, g_m0 = -1e30f;
    #pragma unroll
    for (int s2 = 0; s2 < G; ++s2) {
        if (s2 + 1 < G) loadSeg((s2 + 1) & 1, s2 + 1);
        const float (&d)[10] = f[s2 & 1];
        const int pk = __float_as_int(d[5]);
        const int k = pk & 7, hne = (pk >> 3) & 1;
        g_nc += k; g_hasu |= (pk >> 4) & 1;
        if (d[8] > g_vmax) { g_vmax = d[8]; g_tm = pk >> 5; }
        if (d[9] > g_m0) g_m0 = d[9];
        if (open) {
            if (hne) { cur = fmaxf(cur, fmaxf(ptg, d[6])); ptg = d[7]; }
            if (k > 0 || !hne) { gl[g * 64 + lane] = cur; ++g; open = false; }
        }
        if (k > 0) {
            #pragma unroll
            for (int i = 0; i < 4; ++i)
                if (i < k - 1) { gl[g * 64 + lane] = d[i]; ++g; }
            float last = d[4];                 // select d[k-1]
            if (k == 1) last = d[0];
            else if (k == 2) last = d[1];
            else if (k == 3) last = d[2];
            else if (k == 4) last = d[3];
            cur = last; open = true; ptg = d[7];
        }
    }
    if (open) { gl[g * 64 + lane] = cur; ++g; }        // g == g_nc

    const int label = labels[b * NN + n];

    // pass-2 m_rest: wave-cooperative, rare
    const bool need2 = (label > g_nc) && g_hasu && (label - g_nc >= 2);
    float mrest = g_vmax;                              // full2 surrogate default
    unsigned long long bal = __ballot(need2);
    const float* colbase = vmem + (size_t)b * TT * NN;
    while (bal) {
        const int fl = __ffsll((unsigned long long)bal) - 1;
        bal &= bal - 1;
        const int   nf    = ((bb & 1) << 6) | fl;      // flagged neuron
        const int   tmf   = __shfl(g_tm, fl);
        const float vmaxf = __shfl(g_vmax, fl);
        #pragma unroll
        for (int j = 0; j < 8; ++j) {                  // stage column: 8 loads/lane
            const int t = lane * 8 + j;
            wb[t] = (t < TT) ? colbase[(size_t)t * NN + nf] : -1.0f;
        }
        __syncthreads();                               // single wave: cheap
        int ls2 = -1000, lh = 0; float lm = -1e30f;
        const int u0 = lane * 8;
        for (int t2 = u0 - 10; t2 < u0 + 18; ++t2) {
            const float v = (t2 >= 0 && t2 < 512) ? wb[t2] : -1.0f;
            if (v >= 0.0f) ls2 = t2;
            const int u = t2 - 10;
            if (u >= u0 && u < u0 + 8 && u < TT) {
                if (ls2 < u - 10 && (u < tmf - CC / 2 || u > tmf + CC / 2)) {
                    lh = 1; const float vu = wb[u]; if (vu > lm) lm = vu;
                }
            }
        }
        #pragma unroll
        for (int off = 32; off > 0; off >>= 1) {       // wave reduce
            lm = fmaxf(lm, __shfl_down(lm, off));
            lh |= __shfl_down(lh, off);
        }
        const float res = __shfl(lh ? lm : vmaxf, 0);
        if (lane == fl) mrest = res;
        __syncthreads();
    }

    // branch select
    float contrib = 0.0f;
    if (label > g_nc) {
        if (!g_hasu) contrib = g_vmax;                 // full0 -> vmax
        else {
            const float dE = (float)(label - g_nc);    // >= 1
            contrib = -((g_m0 + (dE - 1.0f) * mrest) / dE);
        }
    } else if (label < g_nc) {
        const int kk = g_nc - label;                   // 1..nc
        float ssum = 0.0f;
        for (int i = 0; i < kk; ++i) {                 // sum kk smallest cluster maxes
            float mn = 1e30f; int mj = 0;
            for (int jj = 0; jj < g_nc; ++jj) {
                const float x = gl[jj * 64 + lane];
                if (x < mn) { mn = x; mj = jj; }
            }
            ssum += mn; gl[mj * 64 + lane] = 1e30f;
        }
        contrib = ssum / (float)kk;
    }

    out[1 + b * NN + n] = (float)g_nc;                 // spike_output

    float w = contrib;
    #pragma unroll
    for (int off = 32; off > 0; off >>= 1) w += __shfl_down(w, off);
    if (lane == 0) atomicAdd(out, w);
}

extern "C" void kernel_launch(void* const* d_in, const int* in_sizes, int n_in,
                              void* d_out, int out_size, void* d_ws, size_t ws_size,
                              hipStream_t stream) {
    const float* vmem   = (const float*)d_in[0];
    // d_in[1] (vlastmem) and d_in[3] (ratio) are unused by the reference forward.
    const int*   labels = (const int*)d_in[2];
    float*       out    = (float*)d_out;
    float*       ws     = (float*)d_ws;   // 256*10*10*128*4 = 13.1 MB

    const int B = in_sizes[2] / NN;       // 256

    hipMemsetAsync(out, 0, sizeof(float), stream);     // zero the loss accumulator
    hipLaunchKernelGGL(seg_scan_kernel, dim3(G, B), dim3(NN), 0, stream, vmem, ws);
    hipLaunchKernelGGL(merge_kernel, dim3(2 * B), dim3(64), 0, stream, vmem, ws, labels, out);
}

// Round 10
// 180.806 us; speedup vs baseline: 1.5960x; 1.3525x over previous
//
#include <hip/hip_runtime.h>

namespace {
constexpr int CC    = 10;                  // cluster gap window C
constexpr int TT    = 500;                 // time steps
constexpr int NN    = 128;                 // neurons per batch row
constexpr int G     = 10;                  // t-segments per trace
constexpr int LSEG  = TT / G;              // 50 core steps
constexpr int HALO  = CC;                  // 10
constexpr int ROWS  = LSEG + 2 * HALO;     // 70 scanned rows
constexpr int CHR   = 8;                   // rows per chunk
constexpr int NCHK  = 9;                   // 9 chunks = 72 staged rows (70 used)
constexpr int RING  = 4;                   // LDS ring slots
constexpr int NSLOT = 10;                  // ws record: 5 cluster maxes + 5 scalars
constexpr int MAXG  = TT / (CC + 1) + 1;   // 46 max global clusters
}

// ---------------- kernel A: producer/consumer wave-specialized scan ----------------
// Waves 2,3: pure memory (float4 global -> LDS ring, reg double-buffered, flag handoff).
// Waves 0,1: pure scan from LDS. Producers have NO compute dependency, so their loads
// stream continuously (16 producer waves/CU at 8 blocks/CU = sustained outstanding
// bytes >> BW*latency). Flag sync via volatile LDS (all waves co-resident: safe).
__global__ __launch_bounds__(256, 8)
void seg_scan_kernel(const float* __restrict__ vmem, float* __restrict__ ws) {
    const int s    = blockIdx.x;           // segment 0..9
    const int b    = blockIdx.y;
    const int tid  = threadIdx.x;
    const int w    = tid >> 6;             // 0,1 = consumers; 2,3 = producers
    const int lane = tid & 63;
    const int a    = s * LSEG;

    __shared__ __align__(16) float ring[RING * CHR * NN];   // 16 KB
    __shared__ float stg[2][5 * 64];                        // 2.5 KB cluster maxes
    __shared__ volatile int prod_cnt[2];
    __shared__ volatile int cons_cnt[2];

    if (tid < 2) { prod_cnt[tid] = 0; cons_cnt[tid] = 0; }
    __syncthreads();

    if (w >= 2) {
        // ---------------- producer: stream 9 chunks of 8 rows ----------------
        const int p    = w - 2;            // producer id 0/1 -> rows p*4 .. p*4+3
        const int rsub = lane >> 4;        // row within my 4
        const int fsub = lane & 15;        // float4 piece within 256-B half-row
        const float4* __restrict__ gb = (const float4*)(vmem + (size_t)b * TT * NN);

        float4 cur0, cur1, nxt0, nxt1;
        auto gload = [&](int c, float4& d0, float4& d1) {
            int t = a - HALO + c * CHR + p * 4 + rsub;
            t = t < 0 ? 0 : (t > TT - 1 ? TT - 1 : t);
            const float4* gp = gb + (size_t)t * 32;          // 32 float4 per row
            d0 = gp[fsub];
            d1 = gp[16 + fsub];
        };
        gload(0, cur0, cur1);
        #pragma unroll
        for (int c = 0; c < NCHK; ++c) {
            if (c + 1 < NCHK) gload(c + 1, nxt0, nxt1);      // prefetch stays in flight
            // ring-slot free? consumers must be done with chunk c-RING
            while (cons_cnt[0] < c - RING + 1 || cons_cnt[1] < c - RING + 1)
                __builtin_amdgcn_s_sleep(1);
            float4* l4 = (float4*)(ring + (c % RING) * (CHR * NN));
            l4[(p * 4 + rsub) * 32 + fsub]      = cur0;
            l4[(p * 4 + rsub) * 32 + 16 + fsub] = cur1;
            __threadfence_block();                           // data before flag
            if (lane == 0) prod_cnt[p] = c + 1;
            cur0 = nxt0; cur1 = nxt1;
        }
    } else {
        // ---------------- consumer: exact scan (R6/R9 semantics) ----------------
        float* sw = stg[w];                // my 64-neuron half
        int   ls = -(1 << 20), lcount = 0, hdne = 0, tmn = 0, hasu = 0;
        float ccm = -1e30f, rmax = -1e30f, hdm = -1e30f, vmx = -1e30f, m0 = -1e30f;
        float h[10];                       // delay line, const-indexed -> registers

        #pragma unroll
        for (int c = 0; c < NCHK; ++c) {
            while (prod_cnt[0] < c + 1 || prod_cnt[1] < c + 1)
                __builtin_amdgcn_s_sleep(1);
            const float* slot = ring + (c % RING) * (CHR * NN);
            #pragma unroll
            for (int j = 0; j < CHR; ++j) {
                const int r = CHR * c + j;                   // compile-time
                if (r >= ROWS) continue;                     // pad rows 70,71
                const int ofs = r - HALO;
                const int t   = a + ofs;
                float x = slot[j * NN + tid];                // tid == neuron (w<2)
                if (s == 0 && r < HALO)        x = -1.0f;    // before t=0
                if (s == G - 1 && ofs >= LSEG) x = -1.0f;    // past t=T
                const bool spike = x >= 0.0f;
                if (ofs >= 0 && ofs < LSEG) {                // core accounting
                    const float rm2     = fmaxf(rmax, x);
                    const bool  recent  = (t - ls <= CC);
                    const bool  isStart = spike && !recent;
                    const bool  contS   = spike && recent;
                    const bool  hd      = contS && (lcount == 0);
                    hdm  = hd ? fmaxf(hdm, rm2) : hdm;
                    hdne = hd ? 1 : hdne;
                    const float folded = fmaxf(ccm, rm2);
                    ccm  = isStart ? x : ((contS && lcount > 0) ? folded : ccm);
                    lcount += isStart ? 1 : 0;
                    rmax = spike ? -1e30f : rm2;
                    if (x > vmx) { vmx = x; tmn = t; }       // strict >: first argmax
                    const int idx = lcount > 0 ? lcount - 1 : 0;
                    sw[idx * 64 + lane] = ccm;               // final write per slot wins
                }
                if (spike) ls = t;                           // halo spikes count for ls
                if (r >= 2 * HALO) {                         // eval u = t-10
                    const float vu = h[r % 10];              // v[t-10]
                    const bool  um = ls < t - 2 * CC;
                    hasu = um ? 1 : hasu;
                    m0   = um ? fmaxf(m0, vu) : m0;
                }
                h[r % 10] = x;
            }
            __threadfence_block();                           // reads done before flag
            if (lane == 0) cons_cnt[w] = c + 1;
        }

        // ---- coalesced output: 10 rows of 512 B ----
        float* __restrict__ wsl = ws + (size_t)(b * G + s) * NSLOT * NN + tid;
        #pragma unroll
        for (int i = 0; i < 5; ++i)
            wsl[i * NN] = (i < lcount) ? sw[i * 64 + lane] : 0.0f;
        const int packed = lcount | (hdne << 3) | (hasu << 4) | (tmn << 5);
        wsl[5 * NN] = __int_as_float(packed);
        wsl[6 * NN] = hdm;     // head-piece max
        wsl[7 * NN] = rmax;    // tail gap max (since last core spike)
        wsl[8 * NN] = vmx;
        wsl[9 * NN] = m0;
    }
}

// ---------------- kernel B: merge segments + loss (1 wave per 64 neurons) ----------------
__global__ __launch_bounds__(64)
void merge_kernel(const float* __restrict__ vmem, const float* __restrict__ ws,
                  const int* __restrict__ labels, float* __restrict__ out) {
    const int bb = blockIdx.x, lane = threadIdx.x;
    const int b = bb >> 1, n = ((bb & 1) << 6) | lane;
    __shared__ float gl[MAXG * 64];        // 11.8 KB compact global cluster list
    __shared__ float wb[512];              // pass-2 column staging

    const float* __restrict__ wsb = ws + (size_t)b * G * NSLOT * NN + n;
    float f[2][10];
    auto loadSeg = [&](int slot, int s2) {
        const float* p = wsb + (size_t)s2 * NSLOT * NN;
        #pragma unroll
        for (int i = 0; i < 10; ++i) f[slot][i] = p[i * NN];
    };
    loadSeg(0, 0);

    int g = 0, g_nc = 0, g_hasu = 0, g_tm = 0;
    bool open = false; float cur = -1e30f, ptg = -1e30f;
    float g_vmax = -1e30f, g_m0 = -1e30f;
    #pragma unroll
    for (int s2 = 0; s2 < G; ++s2) {
        if (s2 + 1 < G) loadSeg((s2 + 1) & 1, s2 + 1);
        const float (&d)[10] = f[s2 & 1];
        const int pk = __float_as_int(d[5]);
        const int k = pk & 7, hne = (pk >> 3) & 1;
        g_nc += k; g_hasu |= (pk >> 4) & 1;
        if (d[8] > g_vmax) { g_vmax = d[8]; g_tm = pk >> 5; }
        if (d[9] > g_m0) g_m0 = d[9];
        if (open) {
            if (hne) { cur = fmaxf(cur, fmaxf(ptg, d[6])); ptg = d[7]; }
            if (k > 0 || !hne) { gl[g * 64 + lane] = cur; ++g; open = false; }
        }
        if (k > 0) {
            #pragma unroll
            for (int i = 0; i < 4; ++i)
                if (i < k - 1) { gl[g * 64 + lane] = d[i]; ++g; }
            float last = d[4];                 // select d[k-1]
            if (k == 1) last = d[0];
            else if (k == 2) last = d[1];
            else if (k == 3) last = d[2];
            else if (k == 4) last = d[3];
            cur = last; open = true; ptg = d[7];
        }
    }
    if (open) { gl[g * 64 + lane] = cur; ++g; }        // g == g_nc

    const int label = labels[b * NN + n];

    // pass-2 m_rest: wave-cooperative, rare
    const bool need2 = (label > g_nc) && g_hasu && (label - g_nc >= 2);
    float mrest = g_vmax;                              // full2 surrogate default
    unsigned long long bal = __ballot(need2);
    const float* colbase = vmem + (size_t)b * TT * NN;
    while (bal) {
        const int fl = __ffsll((unsigned long long)bal) - 1;
        bal &= bal - 1;
        const int   nf    = ((bb & 1) << 6) | fl;      // flagged neuron
        const int   tmf   = __shfl(g_tm, fl);
        const float vmaxf = __shfl(g_vmax, fl);
        #pragma unroll
        for (int j = 0; j < 8; ++j) {                  // stage column: 8 loads/lane
            const int t = lane * 8 + j;
            wb[t] = (t < TT) ? colbase[(size_t)t * NN + nf] : -1.0f;
        }
        __syncthreads();                               // single wave: cheap
        int ls2 = -1000, lh = 0; float lm = -1e30f;
        const int u0 = lane * 8;
        for (int t2 = u0 - 10; t2 < u0 + 18; ++t2) {
            const float v = (t2 >= 0 && t2 < 512) ? wb[t2] : -1.0f;
            if (v >= 0.0f) ls2 = t2;
            const int u = t2 - 10;
            if (u >= u0 && u < u0 + 8 && u < TT) {
                if (ls2 < u - 10 && (u < tmf - CC / 2 || u > tmf + CC / 2)) {
                    lh = 1; const float vu = wb[u]; if (vu > lm) lm = vu;
                }
            }
        }
        #pragma unroll
        for (int off = 32; off > 0; off >>= 1) {       // wave reduce
            lm = fmaxf(lm, __shfl_down(lm, off));
            lh |= __shfl_down(lh, off);
        }
        const float res = __shfl(lh ? lm : vmaxf, 0);
        if (lane == fl) mrest = res;
        __syncthreads();
    }

    // branch select
    float contrib = 0.0f;
    if (label > g_nc) {
        if (!g_hasu) contrib = g_vmax;                 // full0 -> vmax
        else {
            const float dE = (float)(label - g_nc);    // >= 1
            contrib = -((g_m0 + (dE - 1.0f) * mrest) / dE);
        }
    } else if (label < g_nc) {
        const int kk = g_nc - label;                   // 1..nc
        float ssum = 0.0f;
        for (int i = 0; i < kk; ++i) {                 // sum kk smallest cluster maxes
            float mn = 1e30f; int mj = 0;
            for (int jj = 0; jj < g_nc; ++jj) {
                const float x = gl[jj * 64 + lane];
                if (x < mn) { mn = x; mj = jj; }
            }
            ssum += mn; gl[mj * 64 + lane] = 1e30f;
        }
        contrib = ssum / (float)kk;
    }

    out[1 + b * NN + n] = (float)g_nc;                 // spike_output

    float w = contrib;
    #pragma unroll
    for (int off = 32; off > 0; off >>= 1) w += __shfl_down(w, off);
    if (lane == 0) atomicAdd(out, w);
}

extern "C" void kernel_launch(void* const* d_in, const int* in_sizes, int n_in,
                              void* d_out, int out_size, void* d_ws, size_t ws_size,
                              hipStream_t stream) {
    const float* vmem   = (const float*)d_in[0];
    // d_in[1] (vlastmem) and d_in[3] (ratio) are unused by the reference forward.
    const int*   labels = (const int*)d_in[2];
    float*       out    = (float*)d_out;
    float*       ws     = (float*)d_ws;   // 256*10*10*128*4 = 13.1 MB

    const int B = in_sizes[2] / NN;       // 256

    hipMemsetAsync(out, 0, sizeof(float), stream);     // zero the loss accumulator
    hipLaunchKernelGGL(seg_scan_kernel, dim3(G, B), dim3(256), 0, stream, vmem, ws);
    hipLaunchKernelGGL(merge_kernel, dim3(2 * B), dim3(64), 0, stream, vmem, ws, labels, out);
}